// Round 11
// baseline (255.161 us; speedup 1.0000x reference)
//
#include <hip/hip_runtime.h>
#include <math.h>

#define IN_DIM 128
#define HID 64
#define HEADS 4
#define NEG_SLOPE 0.2f
#define LN_EPS 1e-5f

typedef short bf16x8 __attribute__((ext_vector_type(8)));
typedef float f32x4  __attribute__((ext_vector_type(4)));

// ---------- bf16 helpers ----------
__device__ inline unsigned short f2bf(float f) {
    unsigned u = __float_as_uint(f);
    u += 0x7fffu + ((u >> 16) & 1u);     // round-to-nearest-even
    return (unsigned short)(u >> 16);
}
__device__ inline float bf2f(unsigned short s) {
    return __uint_as_float(((unsigned)s) << 16);
}
__device__ inline float leaky(float v) { return v > 0.0f ? v : NEG_SLOPE * v; }

// ---------- fused: zero hist + sampled dtype detect (block 0) + weight pre-pack ----------
// Wt_post: 2560 groups [kg][c][8] (kg<32: 0.25*Wg', else Wp); Wt_xw: 1024 groups (W_gcn).
__global__ void k_init_all(const unsigned long long* ei, int E, int n,
                           int* flag, int* hist,
                           const float* __restrict__ Wg, const float* __restrict__ Wp,
                           const float* __restrict__ Wgcn,
                           unsigned short* __restrict__ Wt_post,
                           unsigned short* __restrict__ Wt_xw) {
    int nzb = (n + 255) >> 8;
    if ((int)blockIdx.x < nzb) {
        int i = blockIdx.x * 256 + threadIdx.x;
        if (i < n) hist[i] = 0;
        if (blockIdx.x == 0) {
            __shared__ int s_bad;
            if (threadIdx.x == 0) s_bad = 0;
            __syncthreads();
            int lim = E < 4096 ? E : 4096;
            int bad = 0;
            for (int k = threadIdx.x; k < lim; k += 256)
                if (ei[k] >= (unsigned long long)n) bad = 1;
            if (bad) s_bad = 1;      // benign race
            __syncthreads();
            if (threadIdx.x == 0) *flag = s_bad ? 0 : 1;   // 1 = genuine int64
        }
    } else {
        int p = (blockIdx.x - nzb) * 256 + threadIdx.x;
        if (p < 2560) {
            int c = p & 63, kg = p >> 6;
            bf16x8 v;
#pragma unroll
            for (int j = 0; j < 8; j++) {
                int k = kg * 8 + j;
                float f;
                if (k < 256) f = 0.25f * Wg[(size_t)(k & 63) * 256 + (k >> 6) * 64 + c];
                else         f = Wp[(size_t)(k - 256) * 64 + c];
                v[j] = (short)f2bf(f);
            }
            *(bf16x8*)(&Wt_post[(size_t)p * 8]) = v;
        } else if (p < 2560 + 1024) {
            int q = p - 2560;
            int c = q & 63, kg = q >> 6;
            bf16x8 v;
#pragma unroll
            for (int j = 0; j < 8; j++)
                v[j] = (short)f2bf(Wgcn[(size_t)(kg * 8 + j) * 64 + c]);
            *(bf16x8*)(&Wt_xw[(size_t)q * 8]) = v;
        }
    }
}

// ---------- dst histogram straight from edge_index (no remap copy) ----------
__global__ void k_hist(const void* ei, int E, const int* flag, int* hist) {
    int i = blockIdx.x * blockDim.x + threadIdx.x;
    if (i >= E) return;
    int is64 = *flag;
    int d;
    if (is64) d = (int)((const long long*)ei)[E + i];
    else      d = ((const int*)ei)[E + i];
    atomicAdd(&hist[d], 1);
}

// ---------- CSR scan ----------
__global__ __launch_bounds__(256) void k_scan1(const int* __restrict__ hist,
                                               int* __restrict__ tmp,
                                               int* __restrict__ partial, int n) {
    __shared__ int s[256];
    int t = threadIdx.x, i = blockIdx.x * 256 + t;
    int v = (i < n) ? hist[i] : 0;
    s[t] = v;
    __syncthreads();
    for (int off = 1; off < 256; off <<= 1) {
        int x = (t >= off) ? s[t - off] : 0;
        __syncthreads();
        s[t] += x;
        __syncthreads();
    }
    tmp[i] = s[t] - v;
    if (t == 255) partial[blockIdx.x] = s[255];
}

// scan of block sums (nb <= 256) + folded att-vector prep
__global__ __launch_bounds__(256) void k_scan2_prep(int* partial, int nb,
                                                    const float* __restrict__ Wg,
                                                    const float* __restrict__ att_s,
                                                    const float* __restrict__ att_d,
                                                    float* __restrict__ w_s,
                                                    float* __restrict__ w_d) {
    __shared__ int s[256];
    int t = threadIdx.x;
    int v = (t < nb) ? partial[t] : 0;
    s[t] = v;
    __syncthreads();
    for (int off = 1; off < 256; off <<= 1) {
        int x = (t >= off) ? s[t - off] : 0;
        __syncthreads();
        s[t] += x;
        __syncthreads();
    }
    if (t < nb) partial[t] = s[t] - v;
    int h = t >> 6, k = t & 63;
    float ss = 0.0f, sd = 0.0f;
    for (int c = 0; c < HID; c++) {
        float w = Wg[(size_t)k * (HEADS * HID) + h * HID + c];
        ss += w * att_s[h * HID + c];
        sd += w * att_d[h * HID + c];
    }
    w_s[h * HID + k] = ss;
    w_d[h * HID + k] = sd;
}

__global__ void k_scan3(const int* __restrict__ tmp, const int* __restrict__ partial,
                        const int* __restrict__ hist, int* __restrict__ row_ptr,
                        int* __restrict__ cursor, float* __restrict__ dinv, int n) {
    int i = blockIdx.x * blockDim.x + threadIdx.x;
    if (i >= n) return;
    int v = tmp[i] + partial[i >> 8];
    row_ptr[i] = v;
    cursor[i] = v;
    dinv[i] = rsqrtf((float)(hist[i] + 1));   // +1 self-loop
}

// ---------- fused: CSR scatter (from raw edge_index) + MFMA x@W_gcn ----------
__global__ __launch_bounds__(256) void k_scatter_xw(const void* ei, int E,
                                                    const int* __restrict__ flag,
                                                    int* __restrict__ cursor,
                                                    int* __restrict__ col,
                                                    int* __restrict__ col_d,
                                                    const float* __restrict__ x,
                                                    const unsigned short* __restrict__ Wt_g,
                                                    const float* __restrict__ dinv,
                                                    unsigned short* __restrict__ xws, int n) {
    __shared__ unsigned short Wt[16 * 64 * 8];   // 16 KB (used by xw half only)
    int nsb = (E + 255) >> 8;
    if ((int)blockIdx.x < nsb) {
        int i = blockIdx.x * 256 + threadIdx.x;
        if (i >= E) return;
        int is64 = *flag;
        int s, d;
        if (is64) { s = (int)((const long long*)ei)[i]; d = (int)((const long long*)ei)[E + i]; }
        else      { s = ((const int*)ei)[i];            d = ((const int*)ei)[E + i]; }
        int pos = atomicAdd(&cursor[d], 1);
        col[pos] = s;
        col_d[pos] = d;
    } else {
        int bx = blockIdx.x - nsb;
        int t = threadIdx.x;
        for (int idx = t; idx < 1024; idx += 256)    // contiguous copy, conflict-free
            *(bf16x8*)(&Wt[idx * 8]) = *(const bf16x8*)(&Wt_g[(size_t)idx * 8]);
        __syncthreads();
        int lane = t & 63;
        int li = lane & 15, quad = lane >> 4;
        int w = t >> 6;
        int r0 = bx * 64 + w * 16;
        int rload = r0 + li; if (rload > n - 1) rload = n - 1;
        f32x4 acc[4];
#pragma unroll
        for (int i = 0; i < 4; i++) acc[i] = (f32x4){0.f, 0.f, 0.f, 0.f};
        const float* xp = x + (size_t)rload * IN_DIM + quad * 8;
#pragma unroll
        for (int ks = 0; ks < 4; ks++) {
            float4 p0 = *(const float4*)(xp + ks * 32);
            float4 p1 = *(const float4*)(xp + ks * 32 + 4);
            bf16x8 a;
            a[0] = (short)f2bf(p0.x); a[1] = (short)f2bf(p0.y);
            a[2] = (short)f2bf(p0.z); a[3] = (short)f2bf(p0.w);
            a[4] = (short)f2bf(p1.x); a[5] = (short)f2bf(p1.y);
            a[6] = (short)f2bf(p1.z); a[7] = (short)f2bf(p1.w);
            int kg = ks * 4 + quad;
#pragma unroll
            for (int tt = 0; tt < 4; tt++) {
                bf16x8 bfr = *(const bf16x8*)(&Wt[((kg * 64) + tt * 16 + li) * 8]);
                acc[tt] = __builtin_amdgcn_mfma_f32_16x16x32_bf16(a, bfr, acc[tt], 0, 0, 0);
            }
        }
#pragma unroll
        for (int reg = 0; reg < 4; reg++) {
            int r = r0 + quad * 4 + reg;
            if (r >= n) continue;
            float dv = dinv[r];
#pragma unroll
            for (int tt = 0; tt < 4; tt++)
                xws[(size_t)r * HID + tt * 16 + li] = f2bf(acc[tt][reg] * dv);
        }
    }
}

// ---------- GCN gather (unroll 8) + bias/relu + logit dots; h1 kept ONLY as bf16 ----------
__global__ __launch_bounds__(256) void k_gcn(const int* __restrict__ col,
                                             const int* __restrict__ row_ptr,
                                             const int* __restrict__ hist,
                                             const float* __restrict__ dinv,
                                             const unsigned short* __restrict__ xws,
                                             const float* __restrict__ b,
                                             const float* __restrict__ w_s,
                                             const float* __restrict__ w_d,
                                             unsigned short* __restrict__ h1b,
                                             float4* __restrict__ a_s,
                                             float4* __restrict__ a_d, int n) {
    int t = threadIdx.x, c = t & 63;
    int d = blockIdx.x * 4 + (t >> 6);
    if (d >= n) return;
    int start = row_ptr[d], cnt = hist[d];
    float acc = bf2f(xws[(size_t)d * HID + c]);       // self term
    int k = 0;
    for (; k + 7 < cnt; k += 8) {
        int s0 = col[start + k],     s1 = col[start + k + 1];
        int s2 = col[start + k + 2], s3 = col[start + k + 3];
        int s4 = col[start + k + 4], s5 = col[start + k + 5];
        int s6 = col[start + k + 6], s7 = col[start + k + 7];
        float v0 = bf2f(xws[(size_t)s0 * HID + c]);
        float v1 = bf2f(xws[(size_t)s1 * HID + c]);
        float v2 = bf2f(xws[(size_t)s2 * HID + c]);
        float v3 = bf2f(xws[(size_t)s3 * HID + c]);
        float v4 = bf2f(xws[(size_t)s4 * HID + c]);
        float v5 = bf2f(xws[(size_t)s5 * HID + c]);
        float v6 = bf2f(xws[(size_t)s6 * HID + c]);
        float v7 = bf2f(xws[(size_t)s7 * HID + c]);
        acc += ((v0 + v1) + (v2 + v3)) + ((v4 + v5) + (v6 + v7));
    }
    for (; k < cnt; k++) acc += bf2f(xws[(size_t)col[start + k] * HID + c]);
    float h1c = fmaxf(acc * dinv[d] + b[c], 0.0f);
    h1b[(size_t)d * HID + c] = f2bf(h1c);
    float vs0 = h1c * w_s[c],       vs1 = h1c * w_s[64 + c];
    float vs2 = h1c * w_s[128 + c], vs3 = h1c * w_s[192 + c];
    float vd0 = h1c * w_d[c],       vd1 = h1c * w_d[64 + c];
    float vd2 = h1c * w_d[128 + c], vd3 = h1c * w_d[192 + c];
    for (int o = 32; o > 0; o >>= 1) {
        vs0 += __shfl_xor(vs0, o, 64); vs1 += __shfl_xor(vs1, o, 64);
        vs2 += __shfl_xor(vs2, o, 64); vs3 += __shfl_xor(vs3, o, 64);
        vd0 += __shfl_xor(vd0, o, 64); vd1 += __shfl_xor(vd1, o, 64);
        vd2 += __shfl_xor(vd2, o, 64); vd3 += __shfl_xor(vd3, o, 64);
    }
    if (c == 0) {
        a_s[d] = make_float4(vs0, vs1, vs2, vs3);
        a_d[d] = make_float4(vd0, vd1, vd2, vd3);
    }
}

// ---------- per-edge softmax weights (edge-parallel) ----------
__global__ void k_ew(const int* __restrict__ col, const int* __restrict__ col_d,
                     const float4* __restrict__ a_s, const float4* __restrict__ a_d,
                     float4* __restrict__ wbuf, int E) {
    int i = blockIdx.x * blockDim.x + threadIdx.x;
    if (i >= E) return;
    int s = col[i], d = col_d[i];
    float4 as = a_s[s], ad = a_d[d];
    float4 r;
    r.x = __expf(leaky(as.x + ad.x));
    r.y = __expf(leaky(as.y + ad.y));
    r.z = __expf(leaky(as.z + ad.z));
    r.w = __expf(leaky(as.w + ad.w));
    wbuf[i] = r;
}

// ---------- attention aggregation of h1 (unroll 8); X is 256 cols (S only) ----------
__global__ __launch_bounds__(256) void k_attn(const int* __restrict__ col,
                                              const int* __restrict__ row_ptr,
                                              const int* __restrict__ hist,
                                              const float4* __restrict__ a_s,
                                              const float4* __restrict__ a_d,
                                              const float4* __restrict__ wbuf,
                                              const unsigned short* __restrict__ h1b,
                                              unsigned short* __restrict__ X, int n) {
    int t = threadIdx.x, c = t & 63;
    int d = blockIdx.x * 4 + (t >> 6);
    if (d >= n) return;
    float4 ad = a_d[d];
    float4 asd = a_s[d];
    float w0 = __expf(leaky(asd.x + ad.x));
    float w1 = __expf(leaky(asd.y + ad.y));
    float w2 = __expf(leaky(asd.z + ad.z));
    float w3 = __expf(leaky(asd.w + ad.w));
    float hs = bf2f(h1b[(size_t)d * HID + c]);
    float A0 = w0 * hs, A1 = w1 * hs, A2 = w2 * hs, A3 = w3 * hs;
    float l0 = w0, l1 = w1, l2 = w2, l3 = w3;
    int start = row_ptr[d], cnt = hist[d];
    int k = 0;
    for (; k + 7 < cnt; k += 8) {
#pragma unroll
        for (int j = 0; j < 8; j += 2) {
            int sa = col[start + k + j], sb = col[start + k + j + 1];
            float4 ea = wbuf[start + k + j], eb = wbuf[start + k + j + 1];
            float ha = bf2f(h1b[(size_t)sa * HID + c]);
            float hb = bf2f(h1b[(size_t)sb * HID + c]);
            A0 += ea.x * ha + eb.x * hb; l0 += ea.x + eb.x;
            A1 += ea.y * ha + eb.y * hb; l1 += ea.y + eb.y;
            A2 += ea.z * ha + eb.z * hb; l2 += ea.z + eb.z;
            A3 += ea.w * ha + eb.w * hb; l3 += ea.w + eb.w;
        }
    }
    for (; k < cnt; k++) {
        int s0 = col[start + k];
        float4 e0 = wbuf[start + k];
        float hv0 = bf2f(h1b[(size_t)s0 * HID + c]);
        A0 += e0.x * hv0; l0 += e0.x;
        A1 += e0.y * hv0; l1 += e0.y;
        A2 += e0.z * hv0; l2 += e0.z;
        A3 += e0.w * hv0; l3 += e0.w;
    }
    size_t base = (size_t)d * 256;
    X[base + c]       = f2bf(A0 / l0);
    X[base + 64 + c]  = f2bf(A1 / l1);
    X[base + 128 + c] = f2bf(A2 / l2);
    X[base + 192 + c] = f2bf(A3 / l3);
}

// ---------- post: MFMA GEMM [X(256) | h1b(64)] @ pre-packed W + relu/residual/LN ----------
// 128 rows/block (2 row-tiles/wave); ks 0..7 A-frags from X, ks 8..9 from h1b.
__global__ __launch_bounds__(256) void k_post(const unsigned short* __restrict__ Wt_g,
                                              const unsigned short* __restrict__ X,
                                              const unsigned short* __restrict__ h1b,
                                              const float* __restrict__ bp,
                                              const float* __restrict__ bg,
                                              const float* __restrict__ gamma,
                                              const float* __restrict__ beta,
                                              float* __restrict__ out, int n) {
    __shared__ unsigned short Wt[2560 * 8];   // 40 KB
    int t = threadIdx.x;
    for (int idx = t; idx < 2560; idx += 256)   // contiguous copy, conflict-free
        *(bf16x8*)(&Wt[idx * 8]) = *(const bf16x8*)(&Wt_g[(size_t)idx * 8]);
    __syncthreads();

    int lane = t & 63;
    int li = lane & 15, quad = lane >> 4;
    int w = t >> 6;
    int rbase = blockIdx.x * 128 + w * 32;       // 32 rows per wave (2 tiles)

    f32x4 acc_a[2][4], acc_h[2][4];
#pragma unroll
    for (int rt = 0; rt < 2; rt++)
#pragma unroll
        for (int i = 0; i < 4; i++) {
            acc_a[rt][i] = (f32x4){0.f, 0.f, 0.f, 0.f};
            acc_h[rt][i] = (f32x4){0.f, 0.f, 0.f, 0.f};
        }
#pragma unroll
    for (int ks = 0; ks < 10; ks++) {
        int kg = ks * 4 + quad;
        bf16x8 b0 = *(const bf16x8*)(&Wt[((kg * 64) + 0 * 16 + li) * 8]);
        bf16x8 b1 = *(const bf16x8*)(&Wt[((kg * 64) + 1 * 16 + li) * 8]);
        bf16x8 b2 = *(const bf16x8*)(&Wt[((kg * 64) + 2 * 16 + li) * 8]);
        bf16x8 b3 = *(const bf16x8*)(&Wt[((kg * 64) + 3 * 16 + li) * 8]);
#pragma unroll
        for (int rt = 0; rt < 2; rt++) {
            int row = rbase + rt * 16 + li;
            bf16x8 a;
            if (ks < 8)
                a = *(const bf16x8*)(X + (size_t)row * 256 + quad * 8 + ks * 32);
            else
                a = *(const bf16x8*)(h1b + (size_t)row * HID + quad * 8 + (ks - 8) * 32);
            if (ks < 8) {
                acc_a[rt][0] = __builtin_amdgcn_mfma_f32_16x16x32_bf16(a, b0, acc_a[rt][0], 0, 0, 0);
                acc_a[rt][1] = __builtin_amdgcn_mfma_f32_16x16x32_bf16(a, b1, acc_a[rt][1], 0, 0, 0);
                acc_a[rt][2] = __builtin_amdgcn_mfma_f32_16x16x32_bf16(a, b2, acc_a[rt][2], 0, 0, 0);
                acc_a[rt][3] = __builtin_amdgcn_mfma_f32_16x16x32_bf16(a, b3, acc_a[rt][3], 0, 0, 0);
            } else {
                acc_h[rt][0] = __builtin_amdgcn_mfma_f32_16x16x32_bf16(a, b0, acc_h[rt][0], 0, 0, 0);
                acc_h[rt][1] = __builtin_amdgcn_mfma_f32_16x16x32_bf16(a, b1, acc_h[rt][1], 0, 0, 0);
                acc_h[rt][2] = __builtin_amdgcn_mfma_f32_16x16x32_bf16(a, b2, acc_h[rt][2], 0, 0, 0);
                acc_h[rt][3] = __builtin_amdgcn_mfma_f32_16x16x32_bf16(a, b3, acc_h[rt][3], 0, 0, 0);
            }
        }
    }
    float bgv[4], bpv[4], gv[4], btv[4];
#pragma unroll
    for (int tt = 0; tt < 4; tt++) {
        int c = tt * 16 + li;
        bgv[tt] = bg[c]; bpv[tt] = bp[c]; gv[tt] = gamma[c]; btv[tt] = beta[c];
    }
#pragma unroll
    for (int rt = 0; rt < 2; rt++) {
#pragma unroll
        for (int reg = 0; reg < 4; reg++) {
            int r = rbase + rt * 16 + quad * 4 + reg;
            bool ok = (r < n);
            float hv[4];
            float s1 = 0.0f, s2 = 0.0f;
#pragma unroll
            for (int tt = 0; tt < 4; tt++) {
                int c = tt * 16 + li;
                float h1c = ok ? bf2f(h1b[(size_t)r * HID + c]) : 0.0f;
                float h2 = fmaxf(acc_a[rt][tt][reg] + bgv[tt], 0.0f);
                float h = h1c + h2 + acc_h[rt][tt][reg] + bpv[tt];
                hv[tt] = h;
                s1 += h; s2 += h * h;
            }
            for (int o = 8; o > 0; o >>= 1) {
                s1 += __shfl_xor(s1, o, 64);
                s2 += __shfl_xor(s2, o, 64);
            }
            float mu = s1 * (1.0f / 64.0f);
            float var = s2 * (1.0f / 64.0f) - mu * mu;
            float rs = rsqrtf(var + LN_EPS);
            if (ok) {
#pragma unroll
                for (int tt = 0; tt < 4; tt++) {
                    int c = tt * 16 + li;
                    out[(size_t)r * HID + c] = (hv[tt] - mu) * rs * gv[tt] + btv[tt];
                }
            }
        }
    }
}

extern "C" void kernel_launch(void* const* d_in, const int* in_sizes, int n_in,
                              void* d_out, int out_size, void* d_ws, size_t ws_size,
                              hipStream_t stream) {
    int n = in_sizes[0] / IN_DIM;
    int E = in_sizes[1] / 2;

    const float* x     = (const float*)d_in[0];
    const void*  ei    = d_in[1];
    const float* W_gcn = (const float*)d_in[2];
    const float* b_gcn = (const float*)d_in[3];
    const float* W_gat = (const float*)d_in[4];
    const float* att_s = (const float*)d_in[5];
    const float* att_d = (const float*)d_in[6];
    const float* b_gat = (const float*)d_in[7];
    const float* W_p   = (const float*)d_in[8];
    const float* b_p   = (const float*)d_in[9];
    const float* gamma = (const float*)d_in[10];
    const float* beta  = (const float*)d_in[11];

    int n_pad  = ((n + 255) / 256) * 256;
    int nscan  = n_pad / 256;                 // must be <= 256
    int n128   = ((n + 127) / 128) * 128;     // row padding for post tiles
    int nzb    = (n + 255) / 256;
    int nsb    = (E + 255) / 256;

    float* ws = (float*)d_ws;
    size_t off = 0;
    int*   flag    = (int*)(ws + off);  off += 4;
    int*   hist    = (int*)(ws + off);  off += n;
    int*   row_ptr = (int*)(ws + off);  off += n;
    int*   cursor  = (int*)(ws + off);  off += n;
    int*   tmp     = (int*)(ws + off);  off += n_pad;
    int*   partial = (int*)(ws + off);  off += 256;
    int*   colv    = (int*)(ws + off);  off += E;
    int*   col_d   = (int*)(ws + off);  off += E;
    float* dinv    = ws + off;          off += n;
    float* w_s     = ws + off;          off += HEADS * HID;
    float* w_d     = ws + off;          off += HEADS * HID;
    off = (off + 3) & ~(size_t)3;
    unsigned short* Wt_post = (unsigned short*)(ws + off); off += 2560 * 8 / 2;
    unsigned short* Wt_xw   = (unsigned short*)(ws + off); off += 1024 * 8 / 2;
    unsigned short* xws = (unsigned short*)(ws + off); off += (size_t)n * HID / 2;
    off = (off + 3) & ~(size_t)3;
    unsigned short* h1b = (unsigned short*)(ws + off); off += (size_t)n128 * HID / 2;
    off = (off + 3) & ~(size_t)3;
    float4* a_sv   = (float4*)(ws + off); off += (size_t)n * 4;
    float4* a_dv   = (float4*)(ws + off); off += (size_t)n * 4;
    off = (off + 3) & ~(size_t)3;
    float4* wbuf   = (float4*)(ws + off); off += (size_t)E * 4;
    unsigned short* X = (unsigned short*)(ws + off); off += (size_t)n128 * 256 / 2;

    // fused: zero hist + detect dtype + pre-pack weights
    k_init_all<<<nzb + 14, 256, 0, stream>>>((const unsigned long long*)ei, E, n,
                                             flag, hist, W_gat, W_p, W_gcn,
                                             Wt_post, Wt_xw);
    // dst histogram from raw edge_index
    k_hist<<<nsb, 256, 0, stream>>>(ei, E, flag, hist);

    // CSR scan
    k_scan1<<<nscan, 256, 0, stream>>>(hist, tmp, partial, n);
    k_scan2_prep<<<1, 256, 0, stream>>>(partial, nscan, W_gat, att_s, att_d, w_s, w_d);
    k_scan3<<<nscan, 256, 0, stream>>>(tmp, partial, hist, row_ptr, cursor, dinv, n);

    // fused: CSR scatter + MFMA x@W_gcn
    k_scatter_xw<<<nsb + (n + 63) / 64, 256, 0, stream>>>(ei, E, flag, cursor,
                                                          colv, col_d, x, Wt_xw,
                                                          dinv, xws, n);

    // GCN gather + logit dots
    k_gcn<<<(n + 3) / 4, 256, 0, stream>>>(colv, row_ptr, hist, dinv, xws, b_gcn,
                                           w_s, w_d, h1b, a_sv, a_dv, n);

    // per-edge softmax weights (edge-parallel exp)
    k_ew<<<(E + 255) / 256, 256, 0, stream>>>(colv, col_d, a_sv, a_dv, wbuf, E);

    // attention aggregation of h1 -> X (256 cols)
    k_attn<<<(n + 3) / 4, 256, 0, stream>>>(colv, row_ptr, hist, a_sv, a_dv,
                                            wbuf, h1b, X, n);

    // MFMA post GEMM + relu/residual/LN
    k_post<<<(n + 127) / 128, 256, 0, stream>>>(Wt_post, X, h1b, b_p, b_gat,
                                                gamma, beta, (float*)d_out, n);
}

// Round 12
// 240.595 us; speedup vs baseline: 1.0605x; 1.0605x over previous
//
#include <hip/hip_runtime.h>
#include <math.h>

#define IN_DIM 128
#define HID 64
#define HEADS 4
#define NEG_SLOPE 0.2f
#define LN_EPS 1e-5f

typedef short bf16x8 __attribute__((ext_vector_type(8)));
typedef float f32x4  __attribute__((ext_vector_type(4)));

// ---------- bf16 helpers ----------
__device__ inline unsigned short f2bf(float f) {
    unsigned u = __float_as_uint(f);
    u += 0x7fffu + ((u >> 16) & 1u);     // round-to-nearest-even
    return (unsigned short)(u >> 16);
}
__device__ inline float bf2f(unsigned short s) {
    return __uint_as_float(((unsigned)s) << 16);
}
__device__ inline float leaky(float v) { return v > 0.0f ? v : NEG_SLOPE * v; }

// ---------- fused: zero hist + sampled dtype detect (block 0) + weight pre-pack ----------
// Wt_post: 2560 groups [kg][c][8] (kg<32: 0.25*Wg', else Wp); Wt_xw: 1024 groups (W_gcn).
__global__ void k_init_all(const unsigned long long* ei, int E, int n,
                           int* flag, int* hist,
                           const float* __restrict__ Wg, const float* __restrict__ Wp,
                           const float* __restrict__ Wgcn,
                           unsigned short* __restrict__ Wt_post,
                           unsigned short* __restrict__ Wt_xw) {
    int nzb = (n + 255) >> 8;
    if ((int)blockIdx.x < nzb) {
        int i = blockIdx.x * 256 + threadIdx.x;
        if (i < n) hist[i] = 0;
        if (blockIdx.x == 0) {
            __shared__ int s_bad;
            if (threadIdx.x == 0) s_bad = 0;
            __syncthreads();
            int lim = E < 4096 ? E : 4096;
            int bad = 0;
            for (int k = threadIdx.x; k < lim; k += 256)
                if (ei[k] >= (unsigned long long)n) bad = 1;
            if (bad) s_bad = 1;      // benign race
            __syncthreads();
            if (threadIdx.x == 0) *flag = s_bad ? 0 : 1;   // 1 = genuine int64
        }
    } else {
        int p = (blockIdx.x - nzb) * 256 + threadIdx.x;
        if (p < 2560) {
            int c = p & 63, kg = p >> 6;
            bf16x8 v;
#pragma unroll
            for (int j = 0; j < 8; j++) {
                int k = kg * 8 + j;
                float f;
                if (k < 256) f = 0.25f * Wg[(size_t)(k & 63) * 256 + (k >> 6) * 64 + c];
                else         f = Wp[(size_t)(k - 256) * 64 + c];
                v[j] = (short)f2bf(f);
            }
            *(bf16x8*)(&Wt_post[(size_t)p * 8]) = v;
        } else if (p < 2560 + 1024) {
            int q = p - 2560;
            int c = q & 63, kg = q >> 6;
            bf16x8 v;
#pragma unroll
            for (int j = 0; j < 8; j++)
                v[j] = (short)f2bf(Wgcn[(size_t)(kg * 8 + j) * 64 + c]);
            *(bf16x8*)(&Wt_xw[(size_t)q * 8]) = v;
        }
    }
}

// ---------- dst histogram straight from edge_index (no remap copy) ----------
__global__ void k_hist(const void* ei, int E, const int* flag, int* hist) {
    int i = blockIdx.x * blockDim.x + threadIdx.x;
    if (i >= E) return;
    int is64 = *flag;
    int d;
    if (is64) d = (int)((const long long*)ei)[E + i];
    else      d = ((const int*)ei)[E + i];
    atomicAdd(&hist[d], 1);
}

// ---------- CSR scan ----------
__global__ __launch_bounds__(256) void k_scan1(const int* __restrict__ hist,
                                               int* __restrict__ tmp,
                                               int* __restrict__ partial, int n) {
    __shared__ int s[256];
    int t = threadIdx.x, i = blockIdx.x * 256 + t;
    int v = (i < n) ? hist[i] : 0;
    s[t] = v;
    __syncthreads();
    for (int off = 1; off < 256; off <<= 1) {
        int x = (t >= off) ? s[t - off] : 0;
        __syncthreads();
        s[t] += x;
        __syncthreads();
    }
    tmp[i] = s[t] - v;
    if (t == 255) partial[blockIdx.x] = s[255];
}

// scan of block sums (nb <= 256) + folded att-vector prep
__global__ __launch_bounds__(256) void k_scan2_prep(int* partial, int nb,
                                                    const float* __restrict__ Wg,
                                                    const float* __restrict__ att_s,
                                                    const float* __restrict__ att_d,
                                                    float* __restrict__ w_s,
                                                    float* __restrict__ w_d) {
    __shared__ int s[256];
    int t = threadIdx.x;
    int v = (t < nb) ? partial[t] : 0;
    s[t] = v;
    __syncthreads();
    for (int off = 1; off < 256; off <<= 1) {
        int x = (t >= off) ? s[t - off] : 0;
        __syncthreads();
        s[t] += x;
        __syncthreads();
    }
    if (t < nb) partial[t] = s[t] - v;
    int h = t >> 6, k = t & 63;
    float ss = 0.0f, sd = 0.0f;
    for (int c = 0; c < HID; c++) {
        float w = Wg[(size_t)k * (HEADS * HID) + h * HID + c];
        ss += w * att_s[h * HID + c];
        sd += w * att_d[h * HID + c];
    }
    w_s[h * HID + k] = ss;
    w_d[h * HID + k] = sd;
}

__global__ void k_scan3(const int* __restrict__ tmp, const int* __restrict__ partial,
                        const int* __restrict__ hist, int* __restrict__ row_ptr,
                        int* __restrict__ cursor, float* __restrict__ dinv, int n) {
    int i = blockIdx.x * blockDim.x + threadIdx.x;
    if (i >= n) return;
    int v = tmp[i] + partial[i >> 8];
    row_ptr[i] = v;
    cursor[i] = v;
    dinv[i] = rsqrtf((float)(hist[i] + 1));   // +1 self-loop
}

// ---------- fused: CSR scatter (from raw edge_index) + MFMA x@W_gcn ----------
__global__ __launch_bounds__(256) void k_scatter_xw(const void* ei, int E,
                                                    const int* __restrict__ flag,
                                                    int* __restrict__ cursor,
                                                    int* __restrict__ col,
                                                    int* __restrict__ col_d,
                                                    const float* __restrict__ x,
                                                    const unsigned short* __restrict__ Wt_g,
                                                    const float* __restrict__ dinv,
                                                    unsigned short* __restrict__ xws, int n) {
    __shared__ unsigned short Wt[16 * 64 * 8];   // 16 KB (used by xw half only)
    int nsb = (E + 255) >> 8;
    if ((int)blockIdx.x < nsb) {
        int i = blockIdx.x * 256 + threadIdx.x;
        if (i >= E) return;
        int is64 = *flag;
        int s, d;
        if (is64) { s = (int)((const long long*)ei)[i]; d = (int)((const long long*)ei)[E + i]; }
        else      { s = ((const int*)ei)[i];            d = ((const int*)ei)[E + i]; }
        int pos = atomicAdd(&cursor[d], 1);
        col[pos] = s;
        col_d[pos] = d;
    } else {
        int bx = blockIdx.x - nsb;
        int t = threadIdx.x;
        for (int idx = t; idx < 1024; idx += 256)    // contiguous copy, conflict-free
            *(bf16x8*)(&Wt[idx * 8]) = *(const bf16x8*)(&Wt_g[(size_t)idx * 8]);
        __syncthreads();
        int lane = t & 63;
        int li = lane & 15, quad = lane >> 4;
        int w = t >> 6;
        int r0 = bx * 64 + w * 16;
        int rload = r0 + li; if (rload > n - 1) rload = n - 1;
        f32x4 acc[4];
#pragma unroll
        for (int i = 0; i < 4; i++) acc[i] = (f32x4){0.f, 0.f, 0.f, 0.f};
        const float* xp = x + (size_t)rload * IN_DIM + quad * 8;
#pragma unroll
        for (int ks = 0; ks < 4; ks++) {
            float4 p0 = *(const float4*)(xp + ks * 32);
            float4 p1 = *(const float4*)(xp + ks * 32 + 4);
            bf16x8 a;
            a[0] = (short)f2bf(p0.x); a[1] = (short)f2bf(p0.y);
            a[2] = (short)f2bf(p0.z); a[3] = (short)f2bf(p0.w);
            a[4] = (short)f2bf(p1.x); a[5] = (short)f2bf(p1.y);
            a[6] = (short)f2bf(p1.z); a[7] = (short)f2bf(p1.w);
            int kg = ks * 4 + quad;
#pragma unroll
            for (int tt = 0; tt < 4; tt++) {
                bf16x8 bfr = *(const bf16x8*)(&Wt[((kg * 64) + tt * 16 + li) * 8]);
                acc[tt] = __builtin_amdgcn_mfma_f32_16x16x32_bf16(a, bfr, acc[tt], 0, 0, 0);
            }
        }
#pragma unroll
        for (int reg = 0; reg < 4; reg++) {
            int r = r0 + quad * 4 + reg;
            if (r >= n) continue;
            float dv = dinv[r];
#pragma unroll
            for (int tt = 0; tt < 4; tt++)
                xws[(size_t)r * HID + tt * 16 + li] = f2bf(acc[tt][reg] * dv);
        }
    }
}

// ---------- GCN gather (unroll 4) + bias/relu + logit dots; h1 kept ONLY as bf16 ----------
__global__ __launch_bounds__(256) void k_gcn(const int* __restrict__ col,
                                             const int* __restrict__ row_ptr,
                                             const int* __restrict__ hist,
                                             const float* __restrict__ dinv,
                                             const unsigned short* __restrict__ xws,
                                             const float* __restrict__ b,
                                             const float* __restrict__ w_s,
                                             const float* __restrict__ w_d,
                                             unsigned short* __restrict__ h1b,
                                             float4* __restrict__ a_s,
                                             float4* __restrict__ a_d, int n) {
    int t = threadIdx.x, c = t & 63;
    int d = blockIdx.x * 4 + (t >> 6);
    if (d >= n) return;
    int start = row_ptr[d], cnt = hist[d];
    float acc = bf2f(xws[(size_t)d * HID + c]);       // self term
    int k = 0;
    for (; k + 3 < cnt; k += 4) {
        int s0 = col[start + k],     s1 = col[start + k + 1];
        int s2 = col[start + k + 2], s3 = col[start + k + 3];
        float v0 = bf2f(xws[(size_t)s0 * HID + c]);
        float v1 = bf2f(xws[(size_t)s1 * HID + c]);
        float v2 = bf2f(xws[(size_t)s2 * HID + c]);
        float v3 = bf2f(xws[(size_t)s3 * HID + c]);
        acc += (v0 + v1) + (v2 + v3);
    }
    for (; k < cnt; k++) acc += bf2f(xws[(size_t)col[start + k] * HID + c]);
    float h1c = fmaxf(acc * dinv[d] + b[c], 0.0f);
    h1b[(size_t)d * HID + c] = f2bf(h1c);
    float vs0 = h1c * w_s[c],       vs1 = h1c * w_s[64 + c];
    float vs2 = h1c * w_s[128 + c], vs3 = h1c * w_s[192 + c];
    float vd0 = h1c * w_d[c],       vd1 = h1c * w_d[64 + c];
    float vd2 = h1c * w_d[128 + c], vd3 = h1c * w_d[192 + c];
    for (int o = 32; o > 0; o >>= 1) {
        vs0 += __shfl_xor(vs0, o, 64); vs1 += __shfl_xor(vs1, o, 64);
        vs2 += __shfl_xor(vs2, o, 64); vs3 += __shfl_xor(vs3, o, 64);
        vd0 += __shfl_xor(vd0, o, 64); vd1 += __shfl_xor(vd1, o, 64);
        vd2 += __shfl_xor(vd2, o, 64); vd3 += __shfl_xor(vd3, o, 64);
    }
    if (c == 0) {
        a_s[d] = make_float4(vs0, vs1, vs2, vs3);
        a_d[d] = make_float4(vd0, vd1, vd2, vd3);
    }
}

// ---------- per-edge softmax weights (edge-parallel) ----------
__global__ void k_ew(const int* __restrict__ col, const int* __restrict__ col_d,
                     const float4* __restrict__ a_s, const float4* __restrict__ a_d,
                     float4* __restrict__ wbuf, int E) {
    int i = blockIdx.x * blockDim.x + threadIdx.x;
    if (i >= E) return;
    int s = col[i], d = col_d[i];
    float4 as = a_s[s], ad = a_d[d];
    float4 r;
    r.x = __expf(leaky(as.x + ad.x));
    r.y = __expf(leaky(as.y + ad.y));
    r.z = __expf(leaky(as.z + ad.z));
    r.w = __expf(leaky(as.w + ad.w));
    wbuf[i] = r;
}

// ---------- attention aggregation of h1 (unroll 4); X is 256 cols (S only) ----------
__global__ __launch_bounds__(256) void k_attn(const int* __restrict__ col,
                                              const int* __restrict__ row_ptr,
                                              const int* __restrict__ hist,
                                              const float4* __restrict__ a_s,
                                              const float4* __restrict__ a_d,
                                              const float4* __restrict__ wbuf,
                                              const unsigned short* __restrict__ h1b,
                                              unsigned short* __restrict__ X, int n) {
    int t = threadIdx.x, c = t & 63;
    int d = blockIdx.x * 4 + (t >> 6);
    if (d >= n) return;
    float4 ad = a_d[d];
    float4 asd = a_s[d];
    float w0 = __expf(leaky(asd.x + ad.x));
    float w1 = __expf(leaky(asd.y + ad.y));
    float w2 = __expf(leaky(asd.z + ad.z));
    float w3 = __expf(leaky(asd.w + ad.w));
    float hs = bf2f(h1b[(size_t)d * HID + c]);
    float A0 = w0 * hs, A1 = w1 * hs, A2 = w2 * hs, A3 = w3 * hs;
    float l0 = w0, l1 = w1, l2 = w2, l3 = w3;
    int start = row_ptr[d], cnt = hist[d];
    int k = 0;
    for (; k + 3 < cnt; k += 4) {
        int s0 = col[start + k],     s1 = col[start + k + 1];
        int s2 = col[start + k + 2], s3 = col[start + k + 3];
        float4 e0 = wbuf[start + k],     e1 = wbuf[start + k + 1];
        float4 e2 = wbuf[start + k + 2], e3 = wbuf[start + k + 3];
        float hv0 = bf2f(h1b[(size_t)s0 * HID + c]);
        float hv1 = bf2f(h1b[(size_t)s1 * HID + c]);
        float hv2 = bf2f(h1b[(size_t)s2 * HID + c]);
        float hv3 = bf2f(h1b[(size_t)s3 * HID + c]);
        A0 += e0.x * hv0 + e1.x * hv1 + e2.x * hv2 + e3.x * hv3;
        A1 += e0.y * hv0 + e1.y * hv1 + e2.y * hv2 + e3.y * hv3;
        A2 += e0.z * hv0 + e1.z * hv1 + e2.z * hv2 + e3.z * hv3;
        A3 += e0.w * hv0 + e1.w * hv1 + e2.w * hv2 + e3.w * hv3;
        l0 += (e0.x + e1.x) + (e2.x + e3.x);
        l1 += (e0.y + e1.y) + (e2.y + e3.y);
        l2 += (e0.z + e1.z) + (e2.z + e3.z);
        l3 += (e0.w + e1.w) + (e2.w + e3.w);
    }
    for (; k < cnt; k++) {
        int s0 = col[start + k];
        float4 e0 = wbuf[start + k];
        float hv0 = bf2f(h1b[(size_t)s0 * HID + c]);
        A0 += e0.x * hv0; l0 += e0.x;
        A1 += e0.y * hv0; l1 += e0.y;
        A2 += e0.z * hv0; l2 += e0.z;
        A3 += e0.w * hv0; l3 += e0.w;
    }
    size_t base = (size_t)d * 256;
    X[base + c]       = f2bf(A0 / l0);
    X[base + 64 + c]  = f2bf(A1 / l1);
    X[base + 128 + c] = f2bf(A2 / l2);
    X[base + 192 + c] = f2bf(A3 / l3);
}

// ---------- post: MFMA GEMM [X(256) | h1b(64)] @ pre-packed W + relu/residual/LN ----------
// 128 rows/block (2 row-tiles/wave); ks 0..7 A-frags from X, ks 8..9 from h1b.
__global__ __launch_bounds__(256) void k_post(const unsigned short* __restrict__ Wt_g,
                                              const unsigned short* __restrict__ X,
                                              const unsigned short* __restrict__ h1b,
                                              const float* __restrict__ bp,
                                              const float* __restrict__ bg,
                                              const float* __restrict__ gamma,
                                              const float* __restrict__ beta,
                                              float* __restrict__ out, int n) {
    __shared__ unsigned short Wt[2560 * 8];   // 40 KB
    int t = threadIdx.x;
    for (int idx = t; idx < 2560; idx += 256)   // contiguous copy, conflict-free
        *(bf16x8*)(&Wt[idx * 8]) = *(const bf16x8*)(&Wt_g[(size_t)idx * 8]);
    __syncthreads();

    int lane = t & 63;
    int li = lane & 15, quad = lane >> 4;
    int w = t >> 6;
    int rbase = blockIdx.x * 128 + w * 32;       // 32 rows per wave (2 tiles)

    f32x4 acc_a[2][4], acc_h[2][4];
#pragma unroll
    for (int rt = 0; rt < 2; rt++)
#pragma unroll
        for (int i = 0; i < 4; i++) {
            acc_a[rt][i] = (f32x4){0.f, 0.f, 0.f, 0.f};
            acc_h[rt][i] = (f32x4){0.f, 0.f, 0.f, 0.f};
        }
#pragma unroll
    for (int ks = 0; ks < 10; ks++) {
        int kg = ks * 4 + quad;
        bf16x8 b0 = *(const bf16x8*)(&Wt[((kg * 64) + 0 * 16 + li) * 8]);
        bf16x8 b1 = *(const bf16x8*)(&Wt[((kg * 64) + 1 * 16 + li) * 8]);
        bf16x8 b2 = *(const bf16x8*)(&Wt[((kg * 64) + 2 * 16 + li) * 8]);
        bf16x8 b3 = *(const bf16x8*)(&Wt[((kg * 64) + 3 * 16 + li) * 8]);
#pragma unroll
        for (int rt = 0; rt < 2; rt++) {
            int row = rbase + rt * 16 + li;
            bf16x8 a;
            if (ks < 8)
                a = *(const bf16x8*)(X + (size_t)row * 256 + quad * 8 + ks * 32);
            else
                a = *(const bf16x8*)(h1b + (size_t)row * HID + quad * 8 + (ks - 8) * 32);
            if (ks < 8) {
                acc_a[rt][0] = __builtin_amdgcn_mfma_f32_16x16x32_bf16(a, b0, acc_a[rt][0], 0, 0, 0);
                acc_a[rt][1] = __builtin_amdgcn_mfma_f32_16x16x32_bf16(a, b1, acc_a[rt][1], 0, 0, 0);
                acc_a[rt][2] = __builtin_amdgcn_mfma_f32_16x16x32_bf16(a, b2, acc_a[rt][2], 0, 0, 0);
                acc_a[rt][3] = __builtin_amdgcn_mfma_f32_16x16x32_bf16(a, b3, acc_a[rt][3], 0, 0, 0);
            } else {
                acc_h[rt][0] = __builtin_amdgcn_mfma_f32_16x16x32_bf16(a, b0, acc_h[rt][0], 0, 0, 0);
                acc_h[rt][1] = __builtin_amdgcn_mfma_f32_16x16x32_bf16(a, b1, acc_h[rt][1], 0, 0, 0);
                acc_h[rt][2] = __builtin_amdgcn_mfma_f32_16x16x32_bf16(a, b2, acc_h[rt][2], 0, 0, 0);
                acc_h[rt][3] = __builtin_amdgcn_mfma_f32_16x16x32_bf16(a, b3, acc_h[rt][3], 0, 0, 0);
            }
        }
    }
    float bgv[4], bpv[4], gv[4], btv[4];
#pragma unroll
    for (int tt = 0; tt < 4; tt++) {
        int c = tt * 16 + li;
        bgv[tt] = bg[c]; bpv[tt] = bp[c]; gv[tt] = gamma[c]; btv[tt] = beta[c];
    }
#pragma unroll
    for (int rt = 0; rt < 2; rt++) {
#pragma unroll
        for (int reg = 0; reg < 4; reg++) {
            int r = rbase + rt * 16 + quad * 4 + reg;
            bool ok = (r < n);
            float hv[4];
            float s1 = 0.0f, s2 = 0.0f;
#pragma unroll
            for (int tt = 0; tt < 4; tt++) {
                int c = tt * 16 + li;
                float h1c = ok ? bf2f(h1b[(size_t)r * HID + c]) : 0.0f;
                float h2 = fmaxf(acc_a[rt][tt][reg] + bgv[tt], 0.0f);
                float h = h1c + h2 + acc_h[rt][tt][reg] + bpv[tt];
                hv[tt] = h;
                s1 += h; s2 += h * h;
            }
            for (int o = 8; o > 0; o >>= 1) {
                s1 += __shfl_xor(s1, o, 64);
                s2 += __shfl_xor(s2, o, 64);
            }
            float mu = s1 * (1.0f / 64.0f);
            float var = s2 * (1.0f / 64.0f) - mu * mu;
            float rs = rsqrtf(var + LN_EPS);
            if (ok) {
#pragma unroll
                for (int tt = 0; tt < 4; tt++) {
                    int c = tt * 16 + li;
                    out[(size_t)r * HID + c] = (hv[tt] - mu) * rs * gv[tt] + btv[tt];
                }
            }
        }
    }
}

extern "C" void kernel_launch(void* const* d_in, const int* in_sizes, int n_in,
                              void* d_out, int out_size, void* d_ws, size_t ws_size,
                              hipStream_t stream) {
    int n = in_sizes[0] / IN_DIM;
    int E = in_sizes[1] / 2;

    const float* x     = (const float*)d_in[0];
    const void*  ei    = d_in[1];
    const float* W_gcn = (const float*)d_in[2];
    const float* b_gcn = (const float*)d_in[3];
    const float* W_gat = (const float*)d_in[4];
    const float* att_s = (const float*)d_in[5];
    const float* att_d = (const float*)d_in[6];
    const float* b_gat = (const float*)d_in[7];
    const float* W_p   = (const float*)d_in[8];
    const float* b_p   = (const float*)d_in[9];
    const float* gamma = (const float*)d_in[10];
    const float* beta  = (const float*)d_in[11];

    int n_pad  = ((n + 255) / 256) * 256;
    int nscan  = n_pad / 256;                 // must be <= 256
    int n128   = ((n + 127) / 128) * 128;     // row padding for post tiles
    int nzb    = (n + 255) / 256;
    int nsb    = (E + 255) / 256;

    float* ws = (float*)d_ws;
    size_t off = 0;
    int*   flag    = (int*)(ws + off);  off += 4;
    int*   hist    = (int*)(ws + off);  off += n;
    int*   row_ptr = (int*)(ws + off);  off += n;
    int*   cursor  = (int*)(ws + off);  off += n;
    int*   tmp     = (int*)(ws + off);  off += n_pad;
    int*   partial = (int*)(ws + off);  off += 256;
    int*   colv    = (int*)(ws + off);  off += E;
    int*   col_d   = (int*)(ws + off);  off += E;
    float* dinv    = ws + off;          off += n;
    float* w_s     = ws + off;          off += HEADS * HID;
    float* w_d     = ws + off;          off += HEADS * HID;
    off = (off + 3) & ~(size_t)3;
    unsigned short* Wt_post = (unsigned short*)(ws + off); off += 2560 * 8 / 2;
    unsigned short* Wt_xw   = (unsigned short*)(ws + off); off += 1024 * 8 / 2;
    unsigned short* xws = (unsigned short*)(ws + off); off += (size_t)n * HID / 2;
    off = (off + 3) & ~(size_t)3;
    unsigned short* h1b = (unsigned short*)(ws + off); off += (size_t)n128 * HID / 2;
    off = (off + 3) & ~(size_t)3;
    float4* a_sv   = (float4*)(ws + off); off += (size_t)n * 4;
    float4* a_dv   = (float4*)(ws + off); off += (size_t)n * 4;
    off = (off + 3) & ~(size_t)3;
    float4* wbuf   = (float4*)(ws + off); off += (size_t)E * 4;
    unsigned short* X = (unsigned short*)(ws + off); off += (size_t)n128 * 256 / 2;

    // fused: zero hist + detect dtype + pre-pack weights
    k_init_all<<<nzb + 14, 256, 0, stream>>>((const unsigned long long*)ei, E, n,
                                             flag, hist, W_gat, W_p, W_gcn,
                                             Wt_post, Wt_xw);
    // dst histogram from raw edge_index
    k_hist<<<nsb, 256, 0, stream>>>(ei, E, flag, hist);

    // CSR scan
    k_scan1<<<nscan, 256, 0, stream>>>(hist, tmp, partial, n);
    k_scan2_prep<<<1, 256, 0, stream>>>(partial, nscan, W_gat, att_s, att_d, w_s, w_d);
    k_scan3<<<nscan, 256, 0, stream>>>(tmp, partial, hist, row_ptr, cursor, dinv, n);

    // fused: CSR scatter + MFMA x@W_gcn
    k_scatter_xw<<<nsb + (n + 63) / 64, 256, 0, stream>>>(ei, E, flag, cursor,
                                                          colv, col_d, x, Wt_xw,
                                                          dinv, xws, n);

    // GCN gather + logit dots
    k_gcn<<<(n + 3) / 4, 256, 0, stream>>>(colv, row_ptr, hist, dinv, xws, b_gcn,
                                           w_s, w_d, h1b, a_sv, a_dv, n);

    // per-edge softmax weights (edge-parallel exp)
    k_ew<<<(E + 255) / 256, 256, 0, stream>>>(colv, col_d, a_sv, a_dv, wbuf, E);

    // attention aggregation of h1 -> X (256 cols)
    k_attn<<<(n + 3) / 4, 256, 0, stream>>>(colv, row_ptr, hist, a_sv, a_dv,
                                            wbuf, h1b, X, n);

    // MFMA post GEMM + relu/residual/LN
    k_post<<<(n + 127) / 128, 256, 0, stream>>>(Wt_post, X, h1b, b_p, b_gat,
                                                gamma, beta, (float*)d_out, n);
}

// Round 13
// 226.002 us; speedup vs baseline: 1.1290x; 1.0646x over previous
//
#include <hip/hip_runtime.h>
#include <math.h>

#define IN_DIM 128
#define HID 64
#define HEADS 4
#define NEG_SLOPE 0.2f
#define LN_EPS 1e-5f
#define ECAP 512            // LDS edge-weight capacity per attn block (4 dsts)

typedef short bf16x8 __attribute__((ext_vector_type(8)));
typedef float f32x4  __attribute__((ext_vector_type(4)));

// ---------- bf16 helpers ----------
__device__ inline unsigned short f2bf(float f) {
    unsigned u = __float_as_uint(f);
    u += 0x7fffu + ((u >> 16) & 1u);     // round-to-nearest-even
    return (unsigned short)(u >> 16);
}
__device__ inline float bf2f(unsigned short s) {
    return __uint_as_float(((unsigned)s) << 16);
}
__device__ inline float leaky(float v) { return v > 0.0f ? v : NEG_SLOPE * v; }

// ---------- fused: zero hist + dtype detect (block 0) + weight pre-pack + att prep ----------
// roles: [0,nzb) zero+detect; [nzb,nzb+14) pack Wt_post/Wt_xw; nzb+14: w_s/w_d fold.
__global__ void k_init_all(const unsigned long long* ei, int E, int n,
                           int* flag, int* hist,
                           const float* __restrict__ Wg, const float* __restrict__ Wp,
                           const float* __restrict__ Wgcn,
                           const float* __restrict__ att_s, const float* __restrict__ att_d,
                           unsigned short* __restrict__ Wt_post,
                           unsigned short* __restrict__ Wt_xw,
                           float* __restrict__ w_s, float* __restrict__ w_d) {
    int nzb = (n + 255) >> 8;
    int t = threadIdx.x;
    if ((int)blockIdx.x < nzb) {
        int i = blockIdx.x * 256 + t;
        if (i < n) hist[i] = 0;
        if (blockIdx.x == 0) {
            __shared__ int s_bad;
            if (t == 0) s_bad = 0;
            __syncthreads();
            int lim = E < 4096 ? E : 4096;
            int bad = 0;
            for (int k = t; k < lim; k += 256)
                if (ei[k] >= (unsigned long long)n) bad = 1;
            if (bad) s_bad = 1;      // benign race
            __syncthreads();
            if (t == 0) *flag = s_bad ? 0 : 1;   // 1 = genuine int64
        }
        return;
    }
    int role = blockIdx.x - nzb;
    if (role < 14) {
        int p = role * 256 + t;
        if (p < 2560) {
            int c = p & 63, kg = p >> 6;
            bf16x8 v;
#pragma unroll
            for (int j = 0; j < 8; j++) {
                int k = kg * 8 + j;
                float f;
                if (k < 256) f = 0.25f * Wg[(size_t)(k & 63) * 256 + (k >> 6) * 64 + c];
                else         f = Wp[(size_t)(k - 256) * 64 + c];
                v[j] = (short)f2bf(f);
            }
            *(bf16x8*)(&Wt_post[(size_t)p * 8]) = v;
        } else if (p < 2560 + 1024) {
            int q = p - 2560;
            int c = q & 63, kg = q >> 6;
            bf16x8 v;
#pragma unroll
            for (int j = 0; j < 8; j++)
                v[j] = (short)f2bf(Wgcn[(size_t)(kg * 8 + j) * 64 + c]);
            *(bf16x8*)(&Wt_xw[(size_t)q * 8]) = v;
        }
    } else {
        // w_s[h,k] = sum_c Wg[k,h,c]*att_s[h,c]
        int h = t >> 6, k = t & 63;
        float ss = 0.0f, sd = 0.0f;
        for (int c = 0; c < HID; c++) {
            float w = Wg[(size_t)k * (HEADS * HID) + h * HID + c];
            ss += w * att_s[h * HID + c];
            sd += w * att_d[h * HID + c];
        }
        w_s[h * HID + k] = ss;
        w_d[h * HID + k] = sd;
    }
}

// ---------- dst histogram straight from edge_index ----------
__global__ void k_hist(const void* ei, int E, const int* flag, int* hist) {
    int i = blockIdx.x * blockDim.x + threadIdx.x;
    if (i >= E) return;
    int is64 = *flag;
    int d;
    if (is64) d = (int)((const long long*)ei)[E + i];
    else      d = ((const int*)ei)[E + i];
    atomicAdd(&hist[d], 1);
}

// ---------- CSR scan pass 1: per-chunk local exclusive scan + chunk sums ----------
__global__ __launch_bounds__(256) void k_scan1(const int* __restrict__ hist,
                                               int* __restrict__ tmp,
                                               int* __restrict__ partial, int n) {
    __shared__ int s[256];
    int t = threadIdx.x, i = blockIdx.x * 256 + t;
    int v = (i < n) ? hist[i] : 0;
    s[t] = v;
    __syncthreads();
    for (int off = 1; off < 256; off <<= 1) {
        int x = (t >= off) ? s[t - off] : 0;
        __syncthreads();
        s[t] += x;
        __syncthreads();
    }
    tmp[i] = s[t] - v;
    if (t == 255) partial[blockIdx.x] = s[255];
}

// ---------- scan pass 2 (fused): each block scans partials locally + applies ----------
__global__ __launch_bounds__(256) void k_scan_apply(const int* __restrict__ tmp,
                                                    const int* __restrict__ partial,
                                                    const int* __restrict__ hist,
                                                    int* __restrict__ row_ptr,
                                                    int* __restrict__ cursor,
                                                    float* __restrict__ dinv,
                                                    int n, int nscan) {
    __shared__ int s[256];
    __shared__ int excl_s;
    int t = threadIdx.x;
    int v = (t < nscan) ? partial[t] : 0;
    s[t] = v;
    __syncthreads();
    for (int off = 1; off < 256; off <<= 1) {
        int x = (t >= off) ? s[t - off] : 0;
        __syncthreads();
        s[t] += x;
        __syncthreads();
    }
    if (t == 0) excl_s = (blockIdx.x == 0) ? 0 : s[blockIdx.x - 1];
    __syncthreads();
    int excl = excl_s;
    int i = blockIdx.x * 256 + t;
    if (i < n) {
        int v2 = tmp[i] + excl;
        row_ptr[i] = v2;
        cursor[i] = v2;
        dinv[i] = rsqrtf((float)(hist[i] + 1));   // +1 self-loop
    }
}

// ---------- fused: CSR scatter (from raw edge_index) + MFMA x@W_gcn ----------
__global__ __launch_bounds__(256) void k_scatter_xw(const void* ei, int E,
                                                    const int* __restrict__ flag,
                                                    int* __restrict__ cursor,
                                                    int* __restrict__ col,
                                                    const float* __restrict__ x,
                                                    const unsigned short* __restrict__ Wt_g,
                                                    const float* __restrict__ dinv,
                                                    unsigned short* __restrict__ xws, int n) {
    __shared__ unsigned short Wt[16 * 64 * 8];   // 16 KB (used by xw half only)
    int nsb = (E + 255) >> 8;
    if ((int)blockIdx.x < nsb) {
        int i = blockIdx.x * 256 + threadIdx.x;
        if (i >= E) return;
        int is64 = *flag;
        int s, d;
        if (is64) { s = (int)((const long long*)ei)[i]; d = (int)((const long long*)ei)[E + i]; }
        else      { s = ((const int*)ei)[i];            d = ((const int*)ei)[E + i]; }
        int pos = atomicAdd(&cursor[d], 1);
        col[pos] = s;
    } else {
        int bx = blockIdx.x - nsb;
        int t = threadIdx.x;
        for (int idx = t; idx < 1024; idx += 256)    // contiguous copy, conflict-free
            *(bf16x8*)(&Wt[idx * 8]) = *(const bf16x8*)(&Wt_g[(size_t)idx * 8]);
        __syncthreads();
        int lane = t & 63;
        int li = lane & 15, quad = lane >> 4;
        int w = t >> 6;
        int r0 = bx * 64 + w * 16;
        int rload = r0 + li; if (rload > n - 1) rload = n - 1;
        f32x4 acc[4];
#pragma unroll
        for (int i = 0; i < 4; i++) acc[i] = (f32x4){0.f, 0.f, 0.f, 0.f};
        const float* xp = x + (size_t)rload * IN_DIM + quad * 8;
#pragma unroll
        for (int ks = 0; ks < 4; ks++) {
            float4 p0 = *(const float4*)(xp + ks * 32);
            float4 p1 = *(const float4*)(xp + ks * 32 + 4);
            bf16x8 a;
            a[0] = (short)f2bf(p0.x); a[1] = (short)f2bf(p0.y);
            a[2] = (short)f2bf(p0.z); a[3] = (short)f2bf(p0.w);
            a[4] = (short)f2bf(p1.x); a[5] = (short)f2bf(p1.y);
            a[6] = (short)f2bf(p1.z); a[7] = (short)f2bf(p1.w);
            int kg = ks * 4 + quad;
#pragma unroll
            for (int tt = 0; tt < 4; tt++) {
                bf16x8 bfr = *(const bf16x8*)(&Wt[((kg * 64) + tt * 16 + li) * 8]);
                acc[tt] = __builtin_amdgcn_mfma_f32_16x16x32_bf16(a, bfr, acc[tt], 0, 0, 0);
            }
        }
#pragma unroll
        for (int reg = 0; reg < 4; reg++) {
            int r = r0 + quad * 4 + reg;
            if (r >= n) continue;
            float dv = dinv[r];
#pragma unroll
            for (int tt = 0; tt < 4; tt++)
                xws[(size_t)r * HID + tt * 16 + li] = f2bf(acc[tt][reg] * dv);
        }
    }
}

// ---------- GCN gather (unroll 4) + bias/relu + logit dots; h1 kept ONLY as bf16 ----------
__global__ __launch_bounds__(256) void k_gcn(const int* __restrict__ col,
                                             const int* __restrict__ row_ptr,
                                             const int* __restrict__ hist,
                                             const float* __restrict__ dinv,
                                             const unsigned short* __restrict__ xws,
                                             const float* __restrict__ b,
                                             const float* __restrict__ w_s,
                                             const float* __restrict__ w_d,
                                             unsigned short* __restrict__ h1b,
                                             float4* __restrict__ a_s,
                                             float4* __restrict__ a_d, int n) {
    int t = threadIdx.x, c = t & 63;
    int d = blockIdx.x * 4 + (t >> 6);
    if (d >= n) return;
    int start = row_ptr[d], cnt = hist[d];
    float acc = bf2f(xws[(size_t)d * HID + c]);       // self term
    int k = 0;
    for (; k + 3 < cnt; k += 4) {
        int s0 = col[start + k],     s1 = col[start + k + 1];
        int s2 = col[start + k + 2], s3 = col[start + k + 3];
        float v0 = bf2f(xws[(size_t)s0 * HID + c]);
        float v1 = bf2f(xws[(size_t)s1 * HID + c]);
        float v2 = bf2f(xws[(size_t)s2 * HID + c]);
        float v3 = bf2f(xws[(size_t)s3 * HID + c]);
        acc += (v0 + v1) + (v2 + v3);
    }
    for (; k < cnt; k++) acc += bf2f(xws[(size_t)col[start + k] * HID + c]);
    float h1c = fmaxf(acc * dinv[d] + b[c], 0.0f);
    h1b[(size_t)d * HID + c] = f2bf(h1c);
    float vs0 = h1c * w_s[c],       vs1 = h1c * w_s[64 + c];
    float vs2 = h1c * w_s[128 + c], vs3 = h1c * w_s[192 + c];
    float vd0 = h1c * w_d[c],       vd1 = h1c * w_d[64 + c];
    float vd2 = h1c * w_d[128 + c], vd3 = h1c * w_d[192 + c];
    for (int o = 32; o > 0; o >>= 1) {
        vs0 += __shfl_xor(vs0, o, 64); vs1 += __shfl_xor(vs1, o, 64);
        vs2 += __shfl_xor(vs2, o, 64); vs3 += __shfl_xor(vs3, o, 64);
        vd0 += __shfl_xor(vd0, o, 64); vd1 += __shfl_xor(vd1, o, 64);
        vd2 += __shfl_xor(vd2, o, 64); vd3 += __shfl_xor(vd3, o, 64);
    }
    if (c == 0) {
        a_s[d] = make_float4(vs0, vs1, vs2, vs3);
        a_d[d] = make_float4(vd0, vd1, vd2, vd3);
    }
}

// ---------- attention: fused edge-weight phase (LDS) + aggregation (unroll 4) ----------
// Phase 1: block's edges (4 contiguous CSR rows) -> weights edge-parallel into LDS.
// Phase 2: wave w aggregates dst d0+w reading weights via LDS broadcast.
__global__ __launch_bounds__(256) void k_attn(const int* __restrict__ col,
                                              const int* __restrict__ row_ptr,
                                              const int* __restrict__ hist,
                                              const float4* __restrict__ a_s,
                                              const float4* __restrict__ a_d,
                                              const unsigned short* __restrict__ h1b,
                                              unsigned short* __restrict__ X, int n) {
    __shared__ float4 wls[ECAP];   // 8 KB
    __shared__ int    sls[ECAP];   // 2 KB
    __shared__ int    sb[5];
    __shared__ float4 sad[4];
    int t = threadIdx.x;
    int d0 = blockIdx.x * 4;
    if (t == 0) {
        int bptr = row_ptr[d0];
        sb[0] = bptr;
        for (int j = 0; j < 4; j++) {
            int d = d0 + j;
            bptr += (d < n) ? hist[d] : 0;
            sb[j + 1] = bptr;
        }
    }
    if (t < 4 && d0 + t < n) sad[t] = a_d[d0 + t];
    __syncthreads();
    int start0 = sb[0];
    int totc = sb[4] - start0;
    int rel1 = sb[1] - start0, rel2 = sb[2] - start0, rel3 = sb[3] - start0;
    bool fast = (totc <= ECAP);
    if (fast) {
        for (int e = t; e < totc; e += 256) {
            int s = col[start0 + e];
            int j = (e >= rel1) + (e >= rel2) + (e >= rel3);
            float4 as = a_s[s], ad = sad[j];
            float4 w;
            w.x = __expf(leaky(as.x + ad.x));
            w.y = __expf(leaky(as.y + ad.y));
            w.z = __expf(leaky(as.z + ad.z));
            w.w = __expf(leaky(as.w + ad.w));
            wls[e] = w;
            sls[e] = s;
        }
    }
    __syncthreads();
    int c = t & 63, w = t >> 6;
    int d = d0 + w;
    if (d >= n) return;
    float4 ad = sad[w];
    float4 asd = a_s[d];
    // self edge
    float w0 = __expf(leaky(asd.x + ad.x));
    float w1 = __expf(leaky(asd.y + ad.y));
    float w2 = __expf(leaky(asd.z + ad.z));
    float w3 = __expf(leaky(asd.w + ad.w));
    float hs = bf2f(h1b[(size_t)d * HID + c]);
    float A0 = w0 * hs, A1 = w1 * hs, A2 = w2 * hs, A3 = w3 * hs;
    float l0 = w0, l1 = w1, l2 = w2, l3 = w3;
    int lo = sb[w] - start0, hi = sb[w + 1] - start0;
    if (fast) {
        int k = lo;
        for (; k + 3 < hi; k += 4) {
            int s0 = sls[k], s1 = sls[k + 1], s2 = sls[k + 2], s3 = sls[k + 3];
            float4 e0 = wls[k], e1 = wls[k + 1], e2 = wls[k + 2], e3 = wls[k + 3];
            float hv0 = bf2f(h1b[(size_t)s0 * HID + c]);
            float hv1 = bf2f(h1b[(size_t)s1 * HID + c]);
            float hv2 = bf2f(h1b[(size_t)s2 * HID + c]);
            float hv3 = bf2f(h1b[(size_t)s3 * HID + c]);
            A0 += e0.x * hv0 + e1.x * hv1 + e2.x * hv2 + e3.x * hv3;
            A1 += e0.y * hv0 + e1.y * hv1 + e2.y * hv2 + e3.y * hv3;
            A2 += e0.z * hv0 + e1.z * hv1 + e2.z * hv2 + e3.z * hv3;
            A3 += e0.w * hv0 + e1.w * hv1 + e2.w * hv2 + e3.w * hv3;
            l0 += (e0.x + e1.x) + (e2.x + e3.x);
            l1 += (e0.y + e1.y) + (e2.y + e3.y);
            l2 += (e0.z + e1.z) + (e2.z + e3.z);
            l3 += (e0.w + e1.w) + (e2.w + e3.w);
        }
        for (; k < hi; k++) {
            int s0 = sls[k];
            float4 e0 = wls[k];
            float hv0 = bf2f(h1b[(size_t)s0 * HID + c]);
            A0 += e0.x * hv0; l0 += e0.x;
            A1 += e0.y * hv0; l1 += e0.y;
            A2 += e0.z * hv0; l2 += e0.z;
            A3 += e0.w * hv0; l3 += e0.w;
        }
    } else {
        // rare fallback: per-lane weights (correct, slower)
        for (int k = lo; k < hi; k++) {
            int s0 = col[start0 + k];
            float4 as = a_s[s0];
            float u0 = __expf(leaky(as.x + ad.x));
            float u1 = __expf(leaky(as.y + ad.y));
            float u2 = __expf(leaky(as.z + ad.z));
            float u3 = __expf(leaky(as.w + ad.w));
            float hv0 = bf2f(h1b[(size_t)s0 * HID + c]);
            A0 += u0 * hv0; l0 += u0;
            A1 += u1 * hv0; l1 += u1;
            A2 += u2 * hv0; l2 += u2;
            A3 += u3 * hv0; l3 += u3;
        }
    }
    size_t base = (size_t)d * 256;
    X[base + c]       = f2bf(A0 / l0);
    X[base + 64 + c]  = f2bf(A1 / l1);
    X[base + 128 + c] = f2bf(A2 / l2);
    X[base + 192 + c] = f2bf(A3 / l3);
}

// ---------- post: MFMA GEMM [X(256) | h1b(64)] @ pre-packed W + relu/residual/LN ----------
__global__ __launch_bounds__(256) void k_post(const unsigned short* __restrict__ Wt_g,
                                              const unsigned short* __restrict__ X,
                                              const unsigned short* __restrict__ h1b,
                                              const float* __restrict__ bp,
                                              const float* __restrict__ bg,
                                              const float* __restrict__ gamma,
                                              const float* __restrict__ beta,
                                              float* __restrict__ out, int n) {
    __shared__ unsigned short Wt[2560 * 8];   // 40 KB
    int t = threadIdx.x;
    for (int idx = t; idx < 2560; idx += 256)   // contiguous copy, conflict-free
        *(bf16x8*)(&Wt[idx * 8]) = *(const bf16x8*)(&Wt_g[(size_t)idx * 8]);
    __syncthreads();

    int lane = t & 63;
    int li = lane & 15, quad = lane >> 4;
    int w = t >> 6;
    int rbase = blockIdx.x * 128 + w * 32;       // 32 rows per wave (2 tiles)

    f32x4 acc_a[2][4], acc_h[2][4];
#pragma unroll
    for (int rt = 0; rt < 2; rt++)
#pragma unroll
        for (int i = 0; i < 4; i++) {
            acc_a[rt][i] = (f32x4){0.f, 0.f, 0.f, 0.f};
            acc_h[rt][i] = (f32x4){0.f, 0.f, 0.f, 0.f};
        }
#pragma unroll
    for (int ks = 0; ks < 10; ks++) {
        int kg = ks * 4 + quad;
        bf16x8 b0 = *(const bf16x8*)(&Wt[((kg * 64) + 0 * 16 + li) * 8]);
        bf16x8 b1 = *(const bf16x8*)(&Wt[((kg * 64) + 1 * 16 + li) * 8]);
        bf16x8 b2 = *(const bf16x8*)(&Wt[((kg * 64) + 2 * 16 + li) * 8]);
        bf16x8 b3 = *(const bf16x8*)(&Wt[((kg * 64) + 3 * 16 + li) * 8]);
#pragma unroll
        for (int rt = 0; rt < 2; rt++) {
            int row = rbase + rt * 16 + li;
            bf16x8 a;
            if (ks < 8)
                a = *(const bf16x8*)(X + (size_t)row * 256 + quad * 8 + ks * 32);
            else
                a = *(const bf16x8*)(h1b + (size_t)row * HID + quad * 8 + (ks - 8) * 32);
            if (ks < 8) {
                acc_a[rt][0] = __builtin_amdgcn_mfma_f32_16x16x32_bf16(a, b0, acc_a[rt][0], 0, 0, 0);
                acc_a[rt][1] = __builtin_amdgcn_mfma_f32_16x16x32_bf16(a, b1, acc_a[rt][1], 0, 0, 0);
                acc_a[rt][2] = __builtin_amdgcn_mfma_f32_16x16x32_bf16(a, b2, acc_a[rt][2], 0, 0, 0);
                acc_a[rt][3] = __builtin_amdgcn_mfma_f32_16x16x32_bf16(a, b3, acc_a[rt][3], 0, 0, 0);
            } else {
                acc_h[rt][0] = __builtin_amdgcn_mfma_f32_16x16x32_bf16(a, b0, acc_h[rt][0], 0, 0, 0);
                acc_h[rt][1] = __builtin_amdgcn_mfma_f32_16x16x32_bf16(a, b1, acc_h[rt][1], 0, 0, 0);
                acc_h[rt][2] = __builtin_amdgcn_mfma_f32_16x16x32_bf16(a, b2, acc_h[rt][2], 0, 0, 0);
                acc_h[rt][3] = __builtin_amdgcn_mfma_f32_16x16x32_bf16(a, b3, acc_h[rt][3], 0, 0, 0);
            }
        }
    }
    float bgv[4], bpv[4], gv[4], btv[4];
#pragma unroll
    for (int tt = 0; tt < 4; tt++) {
        int c = tt * 16 + li;
        bgv[tt] = bg[c]; bpv[tt] = bp[c]; gv[tt] = gamma[c]; btv[tt] = beta[c];
    }
#pragma unroll
    for (int rt = 0; rt < 2; rt++) {
#pragma unroll
        for (int reg = 0; reg < 4; reg++) {
            int r = rbase + rt * 16 + quad * 4 + reg;
            bool ok = (r < n);
            float hv[4];
            float s1 = 0.0f, s2 = 0.0f;
#pragma unroll
            for (int tt = 0; tt < 4; tt++) {
                int c = tt * 16 + li;
                float h1c = ok ? bf2f(h1b[(size_t)r * HID + c]) : 0.0f;
                float h2 = fmaxf(acc_a[rt][tt][reg] + bgv[tt], 0.0f);
                float h = h1c + h2 + acc_h[rt][tt][reg] + bpv[tt];
                hv[tt] = h;
                s1 += h; s2 += h * h;
            }
            for (int o = 8; o > 0; o >>= 1) {
                s1 += __shfl_xor(s1, o, 64);
                s2 += __shfl_xor(s2, o, 64);
            }
            float mu = s1 * (1.0f / 64.0f);
            float var = s2 * (1.0f / 64.0f) - mu * mu;
            float rs = rsqrtf(var + LN_EPS);
            if (ok) {
#pragma unroll
                for (int tt = 0; tt < 4; tt++) {
                    int c = tt * 16 + li;
                    out[(size_t)r * HID + c] = (hv[tt] - mu) * rs * gv[tt] + btv[tt];
                }
            }
        }
    }
}

extern "C" void kernel_launch(void* const* d_in, const int* in_sizes, int n_in,
                              void* d_out, int out_size, void* d_ws, size_t ws_size,
                              hipStream_t stream) {
    int n = in_sizes[0] / IN_DIM;
    int E = in_sizes[1] / 2;

    const float* x     = (const float*)d_in[0];
    const void*  ei    = d_in[1];
    const float* W_gcn = (const float*)d_in[2];
    const float* b_gcn = (const float*)d_in[3];
    const float* W_gat = (const float*)d_in[4];
    const float* att_s = (const float*)d_in[5];
    const float* att_d = (const float*)d_in[6];
    const float* b_gat = (const float*)d_in[7];
    const float* W_p   = (const float*)d_in[8];
    const float* b_p   = (const float*)d_in[9];
    const float* gamma = (const float*)d_in[10];
    const float* beta  = (const float*)d_in[11];

    int n_pad  = ((n + 255) / 256) * 256;
    int nscan  = n_pad / 256;                 // must be <= 256
    int n128   = ((n + 127) / 128) * 128;     // row padding for post tiles
    int nzb    = (n + 255) / 256;
    int nsb    = (E + 255) / 256;

    float* ws = (float*)d_ws;
    size_t off = 0;
    int*   flag    = (int*)(ws + off);  off += 4;
    int*   hist    = (int*)(ws + off);  off += n;
    int*   row_ptr = (int*)(ws + off);  off += n;
    int*   cursor  = (int*)(ws + off);  off += n;
    int*   tmp     = (int*)(ws + off);  off += n_pad;
    int*   partial = (int*)(ws + off);  off += 256;
    int*   colv    = (int*)(ws + off);  off += E;
    float* dinv    = ws + off;          off += n;
    float* w_s     = ws + off;          off += HEADS * HID;
    float* w_d     = ws + off;          off += HEADS * HID;
    off = (off + 3) & ~(size_t)3;
    unsigned short* Wt_post = (unsigned short*)(ws + off); off += 2560 * 8 / 2;
    unsigned short* Wt_xw   = (unsigned short*)(ws + off); off += 1024 * 8 / 2;
    unsigned short* xws = (unsigned short*)(ws + off); off += (size_t)n * HID / 2;
    off = (off + 3) & ~(size_t)3;
    unsigned short* h1b = (unsigned short*)(ws + off); off += (size_t)n128 * HID / 2;
    off = (off + 3) & ~(size_t)3;
    float4* a_sv   = (float4*)(ws + off); off += (size_t)n * 4;
    float4* a_dv   = (float4*)(ws + off); off += (size_t)n * 4;
    off = (off + 3) & ~(size_t)3;
    unsigned short* X = (unsigned short*)(ws + off); off += (size_t)n128 * 256 / 2;

    // fused: zero hist + detect dtype + pre-pack weights + att-vector fold
    k_init_all<<<nzb + 15, 256, 0, stream>>>((const unsigned long long*)ei, E, n,
                                             flag, hist, W_gat, W_p, W_gcn,
                                             att_s, att_d, Wt_post, Wt_xw, w_s, w_d);
    // dst histogram from raw edge_index
    k_hist<<<nsb, 256, 0, stream>>>(ei, E, flag, hist);

    // CSR scan: 2 kernels (pass 2 fused with apply)
    k_scan1<<<nscan, 256, 0, stream>>>(hist, tmp, partial, n);
    k_scan_apply<<<nscan, 256, 0, stream>>>(tmp, partial, hist, row_ptr, cursor,
                                            dinv, n, nscan);

    // fused: CSR scatter + MFMA x@W_gcn
    k_scatter_xw<<<nsb + (n + 63) / 64, 256, 0, stream>>>(ei, E, flag, cursor,
                                                          colv, x, Wt_xw,
                                                          dinv, xws, n);

    // GCN gather + logit dots
    k_gcn<<<(n + 3) / 4, 256, 0, stream>>>(colv, row_ptr, hist, dinv, xws, b_gcn,
                                           w_s, w_d, h1b, a_sv, a_dv, n);

    // attention: edge weights (LDS, edge-parallel) + aggregation -> X (256 cols)
    k_attn<<<(n + 3) / 4, 256, 0, stream>>>(colv, row_ptr, hist, a_sv, a_dv,
                                            h1b, X, n);

    // MFMA post GEMM + relu/residual/LN
    k_post<<<(n + 127) / 128, 256, 0, stream>>>(Wt_post, X, h1b, b_p, b_gat,
                                                gamma, beta, (float*)d_out, n);
}